// Round 11
// baseline (307.351 us; speedup 1.0000x reference)
//
#include <hip/hip_runtime.h>
#include <math.h>

#define WD 80
#define HW 6400
#define PW 82          // padded row width
#define PPX 6790       // allocated pixels per padded image (82*82=6724 + staging slack)
#define NIMG 8
#define NPAIR 32
#define TSTG 960       // uint4 granules per staged tile = 6 rows * 20 px * 64ch * 2B / 16

typedef short bf16x8 __attribute__((ext_vector_type(8)));
typedef float f32x4 __attribute__((ext_vector_type(4)));

__device__ __forceinline__ float bf2f(unsigned short u) {
    return __uint_as_float(((unsigned)u) << 16);
}
__device__ __forceinline__ unsigned short f2bf(float f) {
    unsigned u = __float_as_uint(f);
    u += 0x7fff + ((u >> 16) & 1);          // RNE
    return (unsigned short)(u >> 16);
}

// ---------------- inverse affine from P ----------------
__device__ __forceinline__ void inv_affine(const float* __restrict__ P, int p, float* a) {
    const float* m = P + p * 16;
    float m00 = m[0], m01 = m[1], m02 = m[3] / 0.8f;
    float m10 = m[4], m11 = m[5], m12 = m[7] / 0.8f;
    float cx = 40.0f, cy = 40.0f;
    float tx = cx - (m00 * cx + m01 * cy) + m02;
    float ty = cy - (m10 * cx + m11 * cy) + m12;
    float id = 1.0f / (m00 * m11 - m01 * m10);
    a[0] =  m11 * id; a[1] = -m01 * id;
    a[3] = -m10 * id; a[4] =  m00 * id;
    a[2] = -(a[0] * tx + a[1] * ty);
    a[5] = -(a[3] * tx + a[4] * ty);
}

// ---------------- mega-prologue: border-zero | mats+mask | weight repack | rot-init ----------------
__global__ __launch_bounds__(256) void prologue_all(
        const float* __restrict__ P, float* __restrict__ mats, float* __restrict__ mask,
        const float* __restrict__ msg_w, const float* __restrict__ gates_w,
        const float* __restrict__ can_w,
        unsigned short* __restrict__ Wn, unsigned short* __restrict__ We,
        unsigned short* __restrict__ Wu, unsigned short* __restrict__ Wc,
        const float* __restrict__ x, unsigned short* __restrict__ bufs) {
    __shared__ float T[64][81];
    int bx = blockIdx.x;
    if (bx < 243) {                       // zero borders of 24 contiguous padded images
        int idx = bx * 256 + threadIdx.x;
        if (idx >= 24 * 324 * 8) return;
        int g = idx & 7;
        int e = (idx >> 3) % 324;
        int img = idx / (324 * 8);
        int pp;
        if (e < 82)       pp = e;
        else if (e < 164) pp = 81 * PW + (e - 82);
        else if (e < 244) pp = (e - 164 + 1) * PW;
        else              pp = (e - 244 + 1) * PW + 81;
        *(uint4*)(bufs + ((size_t)img * PPX + pp) * 64 + g * 8) = (uint4){0, 0, 0, 0};
        return;
    }
    bx -= 243;
    if (bx < 32) {                        // mats + nearest-mask
        int p = bx;
        float a[6];
        inv_affine(P, p, a);
        if (threadIdx.x < 6) mats[p * 6 + threadIdx.x] = a[threadIdx.x];
        for (int q = threadIdx.x; q < HW; q += blockDim.x) {
            float xx = (float)(q % WD), yy = (float)(q / WD);
            float sx = a[0] * xx + a[1] * yy + a[2];
            float sy = a[3] * xx + a[4] * yy + a[5];
            int ix = (int)rintf(sx), iy = (int)rintf(sy);
            mask[p * HW + q] = (ix >= 0 && ix < WD && iy >= 0 && iy < WD) ? 1.0f : 0.0f;
        }
        return;
    }
    bx -= 32;
    if (bx < 864) {                       // weight repack: dst[tap][co][cin]
        int t = bx * 256 + threadIdx.x;
        if (t >= 221184) return;
        const float* src; unsigned short* dst;
        int cin_n, co_off, ci_off, stride, u;
        if (t < 36864)       { src = msg_w;   dst = Wn; cin_n = 64;  co_off = 0;  ci_off = 0;  stride = 1152; u = t; }
        else if (t < 73728)  { src = msg_w;   dst = We; cin_n = 64;  co_off = 0;  ci_off = 64; stride = 1152; u = t - 36864; }
        else if (t < 147456) { src = gates_w; dst = Wu; cin_n = 128; co_off = 64; ci_off = 0;  stride = 1728; u = t - 73728; }
        else                 { src = can_w;   dst = Wc; cin_n = 128; co_off = 0;  ci_off = 0;  stride = 1728; u = t - 147456; }
        int ci = u % cin_n;
        int co = (u / cin_n) & 63;
        int tap = u / (cin_n * 64);
        dst[u] = f2bf(src[(size_t)(co_off + co) * stride + (ci_off + ci) * 9 + tap]);
        return;
    }
    bx -= 864;                            // rot-init via LDS transpose (640 blocks)
    int img = bx / 80, hh = bx % 80;
    int tid = threadIdx.x;
    for (int idx = tid; idx < 64 * 80; idx += 256) {
        int c = idx / 80, ww = idx % 80;
        T[c][ww] = x[((size_t)(img * 64 + c) * 80 + hh) * 80 + ww];
    }
    __syncthreads();
    int b = 79 - hh;
    for (int idx = tid; idx < 80 * 64; idx += 256) {
        int a = idx >> 6, ch = idx & 63;
        bufs[((size_t)img * PPX + (a + 1) * PW + (b + 1)) * 64 + ch] = f2bf(T[ch][a]);
    }
}

// ---------------- tile decode ----------------
struct TileInfo { int x0, y0, t, b, img; int ps[4]; };
__device__ __forceinline__ void decode_tile(int tt, int only0, TileInfo& ti) {
    int bx = tt % 5, by = (tt / 5) % 20;
    ti.t = tt / 100;
    ti.x0 = bx * 16; ti.y0 = by * 4;
    int b = only0 ? ti.t : (ti.t >> 2), j = only0 ? 0 : (ti.t & 3);
    ti.b = b;
    ti.img = only0 ? ti.t * 4 : ti.t;
#pragma unroll
    for (int i = 0; i < 4; ++i) {
        int k = only0 ? (b * 4 + i) : ((b * 4 + i) * 4 + j);
        ti.ps[i] = only0 ? k * 4 : k;
    }
}

// ---------------- async staged halo tile: 6 rows x 20 px x 64 ch, swizzled ----------------
__device__ __forceinline__ void stage_t(const unsigned short* __restrict__ src,
                                        int x0, int y0, uint4* bufbase, int tid) {
    const int lane = tid & 63;
    const int wv = tid >> 6;
    for (int c = wv; c < TSTG / 64; c += 4) {
        int s = c * 64 + lane;
        int q = s >> 3;
        int yl = q / 20, xl = q - yl * 20;
        int g = (s & 7) ^ (q & 7);
        const unsigned short* gp = src + ((y0 + yl) * PW + x0 + xl) * 64 + g * 8;
        __builtin_amdgcn_global_load_lds(
            (const __attribute__((address_space(1))) unsigned int*)gp,
            (__attribute__((address_space(3))) unsigned int*)(bufbase + c * 64),
            16, 0, 0);
    }
}

// ---------------- fused bilinear-warp staging: gather + blend + swizzled ds_write ----------------
__device__ __forceinline__ void stage_warp(const unsigned short* __restrict__ src,
        const float* __restrict__ am, int x0, int y0, uint4* bufbase, int tid) {
    float a0 = am[0], a1 = am[1], a2 = am[2], a3 = am[3], a4 = am[4], a5 = am[5];
    for (int idx = tid; idx < TSTG; idx += 256) {
        int q = idx >> 3, g = idx & 7;
        int yl = q / 20, xl = q - yl * 20;
        int ux = x0 + xl - 1, uy = y0 + yl - 1;     // unpadded coords
        uint4 v = {0, 0, 0, 0};
        if ((unsigned)ux < WD && (unsigned)uy < WD) {
            float sx = a0 * ux + a1 * uy + a2;
            float sy = a3 * ux + a4 * uy + a5;
            float fxf = floorf(sx), fyf = floorf(sy);
            float fx = sx - fxf, fy = sy - fyf;
            int ix = (int)fxf, iy = (int)fyf;
            float w00 = (1.f - fx) * (1.f - fy), w10 = fx * (1.f - fy);
            float w01 = (1.f - fx) * fy,         w11 = fx * fy;
            bool vx0 = (unsigned)ix < WD, vx1 = (unsigned)(ix + 1) < WD;
            bool vy0 = (unsigned)iy < WD, vy1 = (unsigned)(iy + 1) < WD;
            if (!(vx0 && vy0)) w00 = 0.f;
            if (!(vx1 && vy0)) w10 = 0.f;
            if (!(vx0 && vy1)) w01 = 0.f;
            if (!(vx1 && vy1)) w11 = 0.f;
            int cx0 = min(max(ix, 0), WD - 1), cx1 = min(max(ix + 1, 0), WD - 1);
            int cy0 = min(max(iy, 0), WD - 1), cy1 = min(max(iy + 1, 0), WD - 1);
            const unsigned short* s8 = src + g * 8;
            uint4 c00 = *(const uint4*)(s8 + ((cy0 + 1) * PW + cx0 + 1) * 64);
            uint4 c10 = *(const uint4*)(s8 + ((cy0 + 1) * PW + cx1 + 1) * 64);
            uint4 c01 = *(const uint4*)(s8 + ((cy1 + 1) * PW + cx0 + 1) * 64);
            uint4 c11 = *(const uint4*)(s8 + ((cy1 + 1) * PW + cx1 + 1) * 64);
            const unsigned short* p00 = (const unsigned short*)&c00;
            const unsigned short* p10 = (const unsigned short*)&c10;
            const unsigned short* p01 = (const unsigned short*)&c01;
            const unsigned short* p11 = (const unsigned short*)&c11;
            unsigned short r8[8];
#pragma unroll
            for (int kk = 0; kk < 8; ++kk) {
                float vv = w00 * bf2f(p00[kk]) + w10 * bf2f(p10[kk])
                         + w01 * bf2f(p01[kk]) + w11 * bf2f(p11[kk]);
                r8[kk] = f2bf(vv);
            }
            v = *(const uint4*)r8;
        }
        bufbase[q * 8 + (g ^ (q & 7))] = v;
    }
}

// ---------------- load 18 B-fragments (9 taps x 2 k-slices) into VGPRs ----------------
__device__ __forceinline__ void load_w(const unsigned short* __restrict__ W, int row,
                                       int cinstride, int cin0, int lh, bf16x8* Wf) {
#pragma unroll
    for (int ks = 0; ks < 2; ++ks)
#pragma unroll
        for (int tap = 0; tap < 9; ++tap)
            Wf[ks * 9 + tap] = *(const bf16x8*)(W + (size_t)(tap * 64 + row) * cinstride
                                                + cin0 + ks * 32 + lh * 8);
}

// ---------------- conv pass: wave = 4 rows x 1 cg; A strips reused over ty (1:2) ----------------
__device__ __forceinline__ void conv_pass4(const uint4* __restrict__ buf, const bf16x8* Wf,
                                           int ll, int lh, f32x4* acc) {
#pragma unroll
    for (int ks = 0; ks < 2; ++ks) {
        const int g = ks * 4 + lh;
#pragma unroll
        for (int tx = 0; tx < 3; ++tx) {
            bf16x8 A[6];
#pragma unroll
            for (int s = 0; s < 6; ++s) {
                int q = s * 20 + tx + ll;
                A[s] = *(const bf16x8*)&buf[q * 8 + (g ^ (q & 7))];
            }
#pragma unroll
            for (int ty = 0; ty < 3; ++ty) {
                bf16x8 B = Wf[ks * 9 + ty * 3 + tx];
#pragma unroll
                for (int r = 0; r < 4; ++r)
                    acc[r] = __builtin_amdgcn_mfma_f32_16x16x32_bf16(A[r + ty], B, acc[r], 0, 0, 0);
            }
        }
    }
}

// ---------------- persistent agg (+ fused warp + fused ego), nt tiles per block ----------------
__global__ __launch_bounds__(256, 2) void msg_agg(const unsigned short* __restrict__ Y,
        const float* __restrict__ mats, const float* __restrict__ mask,
        const unsigned short* __restrict__ Wn, const unsigned short* __restrict__ We,
        const float* __restrict__ bias, unsigned short* __restrict__ Gpad,
        int total, int nt, int only0) {
    __shared__ uint4 lds[2 * TSTG];
    __shared__ float lmask[2][4][4][16];
    const int tid = threadIdx.x, lane = tid & 63, wv = tid >> 6;
    const int ll = lane & 15, lh = lane >> 4;
    const int row = wv * 16 + ll;
    const int mi = tid >> 6, mr = (tid >> 4) & 3, mpx = tid & 15;

    TileInfo ti;
    decode_tile(blockIdx.x, only0, ti);
    lmask[0][mi][mr][mpx] = mask[(size_t)ti.ps[mi] * HW + (ti.y0 + mr) * WD + ti.x0 + mpx];
    bf16x8 Wf[18];
    load_w(Wn, row, 64, 0, lh, Wf);
    stage_warp(Y + (size_t)(ti.b * 4) * PPX * 64, mats + ti.ps[0] * 6, ti.x0, ti.y0, lds, tid);
    __syncthreads();

    for (int k = 0; k < nt; ++k) {
        int tt = blockIdx.x + k * gridDim.x;
        if (tt >= total) break;
        const int p = k & 1;
        decode_tile(tt, only0, ti);

        f32x4 tot[4];
#pragma unroll
        for (int r = 0; r < 4; ++r) tot[r] = (f32x4){0.f, 0.f, 0.f, 0.f};

        for (int i = 0; i < 4; ++i) {
            if (i < 3)
                stage_warp(Y + (size_t)(ti.b * 4 + i + 1) * PPX * 64, mats + ti.ps[i + 1] * 6,
                           ti.x0, ti.y0, lds + (p ^ ((i + 1) & 1)) * TSTG, tid);
            else
                stage_t(Y + (size_t)ti.img * PPX * 64, ti.x0, ti.y0, lds + p * TSTG, tid);
            f32x4 acc[4];
#pragma unroll
            for (int r = 0; r < 4; ++r) acc[r] = (f32x4){0.f, 0.f, 0.f, 0.f};
            conv_pass4(lds + (p ^ (i & 1)) * TSTG, Wf, ll, lh, acc);
#pragma unroll
            for (int r = 0; r < 4; ++r)
#pragma unroll
                for (int jj = 0; jj < 4; ++jj)
                    tot[r][jj] += lmask[p][i][r][lh * 4 + jj] * acc[r][jj];
            __syncthreads();
        }

        // ego pass from buf[p] (prefetched during i=3)
        load_w(We, row, 64, 0, lh, Wf);
        f32x4 acc[4];
#pragma unroll
        for (int r = 0; r < 4; ++r) acc[r] = (f32x4){0.f, 0.f, 0.f, 0.f};
        conv_pass4(lds + p * TSTG, Wf, ll, lh, acc);

        // cross-tile prefetch: next tile's sender0 + lmask (into opposite slots)
        int ttn = tt + gridDim.x;
        if (k + 1 < nt && ttn < total) {
            TileInfo tn;
            decode_tile(ttn, only0, tn);
            stage_warp(Y + (size_t)(tn.b * 4) * PPX * 64, mats + tn.ps[0] * 6,
                       tn.x0, tn.y0, lds + (p ^ 1) * TSTG, tid);
            lmask[p ^ 1][mi][mr][mpx] =
                mask[(size_t)tn.ps[mi] * HW + (tn.y0 + mr) * WD + tn.x0 + mpx];
            load_w(Wn, row, 64, 0, lh, Wf);     // restore Wn for next tile
        }

        float bv = bias[row];
#pragma unroll
        for (int r = 0; r < 4; ++r)
#pragma unroll
            for (int jj = 0; jj < 4; ++jj) {
                int px = lh * 4 + jj;
                float msum = lmask[p][0][r][px] + lmask[p][1][r][px]
                           + lmask[p][2][r][px] + lmask[p][3][r][px];
                float val = 0.25f * (tot[r][jj] + msum * (acc[r][jj] + bv));
                Gpad[((size_t)ti.t * PPX + (ti.y0 + r + 1) * PW + (ti.x0 + px + 1)) * 64 + row]
                    = f2bf(val);
            }
        __syncthreads();
    }
}

// ---------------- persistent GRU conv: nt tiles/block, whole-next-tile prefetch ----------------
__global__ __launch_bounds__(256, 2) void gru_conv(const unsigned short* __restrict__ Ysrc,
        const unsigned short* __restrict__ Gpad,
        const unsigned short* __restrict__ Wu, const unsigned short* __restrict__ Wc,
        const float* __restrict__ bu, const float* __restrict__ bc,
        unsigned short* __restrict__ Ydst, int total, int nt, int only0) {
    __shared__ uint4 lds[4 * TSTG];     // {Y,G} x double-buffer = 61440 B
    const int tid = threadIdx.x, lane = tid & 63, wv = tid >> 6;
    const int ll = lane & 15, lh = lane >> 4;
    const int row = wv * 16 + ll;

    TileInfo ti;
    decode_tile(blockIdx.x, only0, ti);
    stage_t(Ysrc + (size_t)ti.img * PPX * 64, ti.x0, ti.y0, lds, tid);
    stage_t(Gpad + (size_t)ti.t * PPX * 64, ti.x0, ti.y0, lds + TSTG, tid);
    bf16x8 Wf[18];
    load_w(Wu, row, 128, 0, lh, Wf);

    for (int k = 0; k < nt; ++k) {
        int tt = blockIdx.x + k * gridDim.x;
        if (tt >= total) break;
        decode_tile(tt, only0, ti);
        uint4* cur = lds + (k & 1) * 2 * TSTG;
        __syncthreads();                 // staging for this tile complete
        int ttn = tt + gridDim.x;
        if (k + 1 < nt && ttn < total) { // prefetch next tile under this tile's convs
            TileInfo tn;
            decode_tile(ttn, only0, tn);
            uint4* nxt = lds + ((k + 1) & 1) * 2 * TSTG;
            stage_t(Ysrc + (size_t)tn.img * PPX * 64, tn.x0, tn.y0, nxt, tid);
            stage_t(Gpad + (size_t)tn.t * PPX * 64, tn.x0, tn.y0, nxt + TSTG, tid);
        }

        f32x4 aU[4], aC[4];
#pragma unroll
        for (int r = 0; r < 4; ++r) {
            aU[r] = (f32x4){0.f, 0.f, 0.f, 0.f};
            aC[r] = (f32x4){0.f, 0.f, 0.f, 0.f};
        }
        conv_pass4(cur, Wf, ll, lh, aU);
        load_w(Wu, row, 128, 64, lh, Wf);
        conv_pass4(cur + TSTG, Wf, ll, lh, aU);
        load_w(Wc, row, 128, 0, lh, Wf);
        conv_pass4(cur, Wf, ll, lh, aC);
        load_w(Wc, row, 128, 64, lh, Wf);
        conv_pass4(cur + TSTG, Wf, ll, lh, aC);
        load_w(Wu, row, 128, 0, lh, Wf);     // restore for next tile

        float ub = bu[row], cb = bc[row];
#pragma unroll
        for (int r = 0; r < 4; ++r)
#pragma unroll
            for (int jj = 0; jj < 4; ++jj) {
                int x = ti.x0 + lh * 4 + jj;
                float u = 1.f / (1.f + __expf(-(aU[r][jj] + ub)));
                float e2 = __expf(2.f * (aC[r][jj] + cb));
                float c = (e2 - 1.f) / (e2 + 1.f);
                Ydst[((size_t)ti.img * PPX + (ti.y0 + r + 1) * PW + (x + 1)) * 64 + row]
                    = f2bf(u * c);
            }
    }
}

// ---------------- final: out[b,h,w,o] = sum_c Ypad[4b][w][79-h][c]*mlp_w[o,c] + mlp_b[o] ----------------
__global__ void final_mlp(const unsigned short* __restrict__ yfin, const float* __restrict__ mw,
                          const float* __restrict__ mb, float* __restrict__ out) {
    int t = blockIdx.x * blockDim.x + threadIdx.x;
    if (t >= 2 * HW * 64) return;
    int o  = t & 63;
    int wv = (t >> 6) % WD;
    int h  = ((t >> 6) / WD) % WD;
    int b  = t / (HW * 64);
    const unsigned short* src = yfin + ((size_t)(b * 4) * PPX + (wv + 1) * PW + (80 - h)) * 64;
    const float* wrow = mw + o * 64;
    float r = mb[o];
#pragma unroll
    for (int c8 = 0; c8 < 8; ++c8) {
        bf16x8 v = *(const bf16x8*)(src + c8 * 8);
#pragma unroll
        for (int k = 0; k < 8; ++k)
            r += bf2f(((const unsigned short*)&v)[k]) * wrow[c8 * 8 + k];
    }
    out[t] = r;
}

extern "C" void kernel_launch(void* const* d_in, const int* in_sizes, int n_in,
                              void* d_out, int out_size, void* d_ws, size_t ws_size,
                              hipStream_t stream) {
    const float* x       = (const float*)d_in[0];
    const float* P       = (const float*)d_in[2];
    const float* msg_w   = (const float*)d_in[4];
    const float* msg_b   = (const float*)d_in[5];
    const float* gates_w = (const float*)d_in[6];
    const float* gates_b = (const float*)d_in[7];
    const float* can_w   = (const float*)d_in[8];
    const float* can_b   = (const float*)d_in[9];
    const float* mlp_w   = (const float*)d_in[10];
    const float* mlp_b   = (const float*)d_in[11];
    float* out = (float*)d_out;

    char* wsb = (char*)d_ws;
    float* mats = (float*)wsb;                              // 1024 B
    float* mask = (float*)(wsb + 1024);                     // 819200
    unsigned short* Wn = (unsigned short*)(wsb + 820224);   // 73728
    unsigned short* We = Wn + 36864;                        // 73728
    unsigned short* Wu = We + 36864;                        // 147456
    unsigned short* Wc = Wu + 73728;                        // 147456
    unsigned short* Y0 = Wc + 73728;                        // 8*PPX*128 = 6952960 ┐
    unsigned short* Y1 = Y0 + (size_t)NIMG * PPX * 64;      // 6952960            ├ 24 contiguous images
    unsigned short* Gpad = Y1 + (size_t)NIMG * PPX * 64;    // 6952960            ┘

    // one mega-prologue: border-zero (243) | mats+mask (32) | repack (864) | rot (640)
    prologue_all<<<243 + 32 + 864 + 640, 256, 0, stream>>>(P, mats, mask,
        msg_w, gates_w, can_w, Wn, We, Wu, Wc, x, Y0);

    // ---- iteration 0 (all 8 targets): 800 tiles, persistent 2 tiles/block ----
    msg_agg<<<400, 256, 0, stream>>>(Y0, mats, mask, Wn, We, msg_b, Gpad, 800, 2, 0);
    gru_conv<<<400, 256, 0, stream>>>(Y0, Gpad, Wu, Wc, gates_b + 64, can_b, Y1, 800, 2, 0);

    // ---- iteration 1 (only j=0 targets: images 0 and 4): 200 tiles ----
    msg_agg<<<200, 256, 0, stream>>>(Y1, mats, mask, Wn, We, msg_b, Gpad, 200, 1, 1);
    gru_conv<<<200, 256, 0, stream>>>(Y1, Gpad, Wu, Wc, gates_b + 64, can_b, Y0, 200, 1, 1);

    final_mlp<<<(2 * HW * 64 + 255) / 256, 256, 0, stream>>>(Y0, mlp_w, mlp_b, out);
}

// Round 12
// 230.720 us; speedup vs baseline: 1.3321x; 1.3321x over previous
//
#include <hip/hip_runtime.h>
#include <math.h>

#define WD 80
#define HW 6400
#define PW 82          // padded row width
#define PPX 6790       // allocated pixels per padded image (82*82=6724 + staging slack)
#define NIMG 8
#define NPAIR 32
#define TSTG 960       // uint4 granules per staged tile = 6 rows * 20 px * 64ch * 2B / 16

typedef short bf16x8 __attribute__((ext_vector_type(8)));
typedef float f32x4 __attribute__((ext_vector_type(4)));

__device__ __forceinline__ float bf2f(unsigned short u) {
    return __uint_as_float(((unsigned)u) << 16);
}
__device__ __forceinline__ unsigned short f2bf(float f) {
    unsigned u = __float_as_uint(f);
    u += 0x7fff + ((u >> 16) & 1);          // RNE
    return (unsigned short)(u >> 16);
}

// ---------------- inverse affine from P ----------------
__device__ __forceinline__ void inv_affine(const float* __restrict__ P, int p, float* a) {
    const float* m = P + p * 16;
    float m00 = m[0], m01 = m[1], m02 = m[3] / 0.8f;
    float m10 = m[4], m11 = m[5], m12 = m[7] / 0.8f;
    float cx = 40.0f, cy = 40.0f;
    float tx = cx - (m00 * cx + m01 * cy) + m02;
    float ty = cy - (m10 * cx + m11 * cy) + m12;
    float id = 1.0f / (m00 * m11 - m01 * m10);
    a[0] =  m11 * id; a[1] = -m01 * id;
    a[3] = -m10 * id; a[4] =  m00 * id;
    a[2] = -(a[0] * tx + a[1] * ty);
    a[5] = -(a[3] * tx + a[4] * ty);
}

// ---------------- mega-prologue: border-zero | mats+mask | weight repack | rot-init ----------------
__global__ __launch_bounds__(256) void prologue_all(
        const float* __restrict__ P, float* __restrict__ mats, float* __restrict__ mask,
        const float* __restrict__ msg_w, const float* __restrict__ gates_w,
        const float* __restrict__ can_w,
        unsigned short* __restrict__ Wn, unsigned short* __restrict__ We,
        unsigned short* __restrict__ Wu, unsigned short* __restrict__ Wc,
        const float* __restrict__ x, unsigned short* __restrict__ bufs) {
    __shared__ float T[64][81];
    int bx = blockIdx.x;
    if (bx < 243) {                       // zero borders of 24 contiguous padded images
        int idx = bx * 256 + threadIdx.x;
        if (idx >= 24 * 324 * 8) return;
        int g = idx & 7;
        int e = (idx >> 3) % 324;
        int img = idx / (324 * 8);
        int pp;
        if (e < 82)       pp = e;
        else if (e < 164) pp = 81 * PW + (e - 82);
        else if (e < 244) pp = (e - 164 + 1) * PW;
        else              pp = (e - 244 + 1) * PW + 81;
        *(uint4*)(bufs + ((size_t)img * PPX + pp) * 64 + g * 8) = (uint4){0, 0, 0, 0};
        return;
    }
    bx -= 243;
    if (bx < 32) {                        // mats + nearest-mask
        int p = bx;
        float a[6];
        inv_affine(P, p, a);
        if (threadIdx.x < 6) mats[p * 6 + threadIdx.x] = a[threadIdx.x];
        for (int q = threadIdx.x; q < HW; q += blockDim.x) {
            float xx = (float)(q % WD), yy = (float)(q / WD);
            float sx = a[0] * xx + a[1] * yy + a[2];
            float sy = a[3] * xx + a[4] * yy + a[5];
            int ix = (int)rintf(sx), iy = (int)rintf(sy);
            mask[p * HW + q] = (ix >= 0 && ix < WD && iy >= 0 && iy < WD) ? 1.0f : 0.0f;
        }
        return;
    }
    bx -= 32;
    if (bx < 864) {                       // weight repack: dst[tap][co][cin]
        int t = bx * 256 + threadIdx.x;
        if (t >= 221184) return;
        const float* src; unsigned short* dst;
        int cin_n, co_off, ci_off, stride, u;
        if (t < 36864)       { src = msg_w;   dst = Wn; cin_n = 64;  co_off = 0;  ci_off = 0;  stride = 1152; u = t; }
        else if (t < 73728)  { src = msg_w;   dst = We; cin_n = 64;  co_off = 0;  ci_off = 64; stride = 1152; u = t - 36864; }
        else if (t < 147456) { src = gates_w; dst = Wu; cin_n = 128; co_off = 64; ci_off = 0;  stride = 1728; u = t - 73728; }
        else                 { src = can_w;   dst = Wc; cin_n = 128; co_off = 0;  ci_off = 0;  stride = 1728; u = t - 147456; }
        int ci = u % cin_n;
        int co = (u / cin_n) & 63;
        int tap = u / (cin_n * 64);
        dst[u] = f2bf(src[(size_t)(co_off + co) * stride + (ci_off + ci) * 9 + tap]);
        return;
    }
    bx -= 864;                            // rot-init via LDS transpose (640 blocks)
    int img = bx / 80, hh = bx % 80;
    int tid = threadIdx.x;
    for (int idx = tid; idx < 64 * 80; idx += 256) {
        int c = idx / 80, ww = idx % 80;
        T[c][ww] = x[((size_t)(img * 64 + c) * 80 + hh) * 80 + ww];
    }
    __syncthreads();
    int b = 79 - hh;
    for (int idx = tid; idx < 80 * 64; idx += 256) {
        int a = idx >> 6, ch = idx & 63;
        bufs[((size_t)img * PPX + (a + 1) * PW + (b + 1)) * 64 + ch] = f2bf(T[ch][a]);
    }
}

// ---------------- bilinear warp of pairs into padded warped[k] ----------------
__global__ void warp_pairs(const unsigned short* __restrict__ Ysrc, const float* __restrict__ mats,
                           unsigned short* __restrict__ warped, int total, int only0) {
    int idx = blockIdx.x * blockDim.x + threadIdx.x;
    if (idx >= total) return;
    int g = idx & 7;
    int pp = (idx >> 3) % 6724;
    int k = idx / (6724 * 8);
    int p = only0 ? k * 4 : k;
    int py = pp / PW, pxx = pp % PW;
    uint4 v = {0, 0, 0, 0};
    if (py >= 1 && py <= 80 && pxx >= 1 && pxx <= 80) {
        int y = py - 1, x = pxx - 1;
        const float* a = mats + p * 6;
        float sx = a[0] * x + a[1] * y + a[2];
        float sy = a[3] * x + a[4] * y + a[5];
        float fxf = floorf(sx), fyf = floorf(sy);
        float fx = sx - fxf, fy = sy - fyf;
        int ix = (int)fxf, iy = (int)fyf;
        float w00 = (1.f - fx) * (1.f - fy), w10 = fx * (1.f - fy);
        float w01 = (1.f - fx) * fy,         w11 = fx * fy;
        bool vx0 = (unsigned)ix < WD, vx1 = (unsigned)(ix + 1) < WD;
        bool vy0 = (unsigned)iy < WD, vy1 = (unsigned)(iy + 1) < WD;
        if (!(vx0 && vy0)) w00 = 0.f;
        if (!(vx1 && vy0)) w10 = 0.f;
        if (!(vx0 && vy1)) w01 = 0.f;
        if (!(vx1 && vy1)) w11 = 0.f;
        int cx0 = min(max(ix, 0), WD - 1), cx1 = min(max(ix + 1, 0), WD - 1);
        int cy0 = min(max(iy, 0), WD - 1), cy1 = min(max(iy + 1, 0), WD - 1);
        const unsigned short* src = Ysrc + (size_t)(p >> 2) * PPX * 64 + g * 8;
        uint4 c00 = *(const uint4*)(src + ((cy0 + 1) * PW + cx0 + 1) * 64);
        uint4 c10 = *(const uint4*)(src + ((cy0 + 1) * PW + cx1 + 1) * 64);
        uint4 c01 = *(const uint4*)(src + ((cy1 + 1) * PW + cx0 + 1) * 64);
        uint4 c11 = *(const uint4*)(src + ((cy1 + 1) * PW + cx1 + 1) * 64);
        const unsigned short* p00 = (const unsigned short*)&c00;
        const unsigned short* p10 = (const unsigned short*)&c10;
        const unsigned short* p01 = (const unsigned short*)&c01;
        const unsigned short* p11 = (const unsigned short*)&c11;
        unsigned short r8[8];
#pragma unroll
        for (int kk = 0; kk < 8; ++kk) {
            float vv = w00 * bf2f(p00[kk]) + w10 * bf2f(p10[kk])
                     + w01 * bf2f(p01[kk]) + w11 * bf2f(p11[kk]);
            r8[kk] = f2bf(vv);
        }
        v = *(const uint4*)r8;
    }
    *(uint4*)(warped + ((size_t)k * PPX + pp) * 64 + g * 8) = v;
}

// ---------------- async staged halo tile: 6 rows x 20 px x 64 ch, swizzled ----------------
__device__ __forceinline__ void stage_t(const unsigned short* __restrict__ src,
                                        int x0, int y0, uint4* bufbase, int tid) {
    const int lane = tid & 63;
    const int wv = tid >> 6;
    for (int c = wv; c < TSTG / 64; c += 4) {
        int s = c * 64 + lane;
        int q = s >> 3;
        int yl = q / 20, xl = q - yl * 20;
        int g = (s & 7) ^ (q & 7);
        const unsigned short* gp = src + ((y0 + yl) * PW + x0 + xl) * 64 + g * 8;
        __builtin_amdgcn_global_load_lds(
            (const __attribute__((address_space(1))) unsigned int*)gp,
            (__attribute__((address_space(3))) unsigned int*)(bufbase + c * 64),
            16, 0, 0);
    }
}

// ---------------- load 18 B-fragments (9 taps x 2 k-slices) into VGPRs ----------------
__device__ __forceinline__ void load_w(const unsigned short* __restrict__ W, int row,
                                       int cinstride, int cin0, int lh, bf16x8* Wf) {
#pragma unroll
    for (int ks = 0; ks < 2; ++ks)
#pragma unroll
        for (int tap = 0; tap < 9; ++tap)
            Wf[ks * 9 + tap] = *(const bf16x8*)(W + (size_t)(tap * 64 + row) * cinstride
                                                + cin0 + ks * 32 + lh * 8);
}

// ---------------- conv pass: wave = 4 rows x 1 cg; A strips reused over ty (1:2) ----------------
__device__ __forceinline__ void conv_pass4(const uint4* __restrict__ buf, const bf16x8* Wf,
                                           int ll, int lh, f32x4* acc) {
#pragma unroll
    for (int ks = 0; ks < 2; ++ks) {
        const int g = ks * 4 + lh;
#pragma unroll
        for (int tx = 0; tx < 3; ++tx) {
            bf16x8 A[6];
#pragma unroll
            for (int s = 0; s < 6; ++s) {
                int q = s * 20 + tx + ll;
                A[s] = *(const bf16x8*)&buf[q * 8 + (g ^ (q & 7))];
            }
#pragma unroll
            for (int ty = 0; ty < 3; ++ty) {
                bf16x8 B = Wf[ks * 9 + ty * 3 + tx];
#pragma unroll
                for (int r = 0; r < 4; ++r)
                    acc[r] = __builtin_amdgcn_mfma_f32_16x16x32_bf16(A[r + ty], B, acc[r], 0, 0, 0);
            }
        }
    }
}

// ---------------- agg (+ fused ego): Gpad = 0.25*(sum_i m_i*conv_n(warp_i) + (sum m_i)*(conv_e(y)+b)) ----------------
__global__ __launch_bounds__(256, 2) void msg_agg(const unsigned short* __restrict__ warped,
        const unsigned short* __restrict__ Y, const float* __restrict__ mask,
        const unsigned short* __restrict__ Wn, const unsigned short* __restrict__ We,
        const float* __restrict__ bias, unsigned short* __restrict__ Gpad, int only0) {
    __shared__ uint4 lds[2 * TSTG];
    __shared__ float lmask[4][4][16];
    const int tid = threadIdx.x, lane = tid & 63, wv = tid >> 6;
    const int ll = lane & 15, lh = lane >> 4;
    const int x0 = blockIdx.x * 16, y0 = blockIdx.y * 4;
    const int t = blockIdx.z;
    const int b = only0 ? t : (t >> 2), j = only0 ? 0 : (t & 3);
    const int img = only0 ? t * 4 : t;
    const int row = wv * 16 + ll;          // co handled by this wave

    int ks_[4];
#pragma unroll
    for (int i = 0; i < 4; ++i)
        ks_[i] = only0 ? (b * 4 + i) : ((b * 4 + i) * 4 + j);
    {   // 4*4*16 = 256: one mask element per thread
        int i = tid >> 6, r = (tid >> 4) & 3, px = tid & 15;
        int p = only0 ? ks_[i] * 4 : ks_[i];
        lmask[i][r][px] = mask[(size_t)p * HW + (y0 + r) * WD + x0 + px];
    }
    bf16x8 Wf[18];
    load_w(Wn, row, 64, 0, lh, Wf);
    stage_t(warped + (size_t)ks_[0] * PPX * 64, x0, y0, lds, tid);
    __syncthreads();

    f32x4 tot[4];
#pragma unroll
    for (int r = 0; r < 4; ++r) tot[r] = (f32x4){0.f, 0.f, 0.f, 0.f};

    for (int i = 0; i < 4; ++i) {
        if (i < 3)
            stage_t(warped + (size_t)ks_[i + 1] * PPX * 64, x0, y0, lds + ((i + 1) & 1) * TSTG, tid);
        else
            stage_t(Y + (size_t)img * PPX * 64, x0, y0, lds, tid);   // ego prefetch into buf0
        f32x4 acc[4];
#pragma unroll
        for (int r = 0; r < 4; ++r) acc[r] = (f32x4){0.f, 0.f, 0.f, 0.f};
        conv_pass4(lds + (i & 1) * TSTG, Wf, ll, lh, acc);
#pragma unroll
        for (int r = 0; r < 4; ++r)
#pragma unroll
            for (int jj = 0; jj < 4; ++jj)
                tot[r][jj] += lmask[i][r][lh * 4 + jj] * acc[r][jj];
        __syncthreads();
    }

    // ego pass from buf0 (prefetched during i=3)
    load_w(We, row, 64, 0, lh, Wf);
    f32x4 acc[4];
#pragma unroll
    for (int r = 0; r < 4; ++r) acc[r] = (f32x4){0.f, 0.f, 0.f, 0.f};
    conv_pass4(lds, Wf, ll, lh, acc);

    float bv = bias[row];
#pragma unroll
    for (int r = 0; r < 4; ++r)
#pragma unroll
        for (int jj = 0; jj < 4; ++jj) {
            int px = lh * 4 + jj;
            float msum = lmask[0][r][px] + lmask[1][r][px] + lmask[2][r][px] + lmask[3][r][px];
            float val = 0.25f * (tot[r][jj] + msum * (acc[r][jj] + bv));
            Gpad[((size_t)t * PPX + (y0 + r + 1) * PW + (x0 + px + 1)) * 64 + row] = f2bf(val);
        }
}

// ---------------- GRU conv: wave = 1 cg x 4 rows, single live weight set ----------------
__global__ __launch_bounds__(256, 2) void gru_conv(const unsigned short* __restrict__ Ysrc,
        const unsigned short* __restrict__ Gpad,
        const unsigned short* __restrict__ Wu, const unsigned short* __restrict__ Wc,
        const float* __restrict__ bu, const float* __restrict__ bc,
        unsigned short* __restrict__ Ydst, int only0) {
    __shared__ uint4 lds[2 * TSTG];
    const int tid = threadIdx.x, lane = tid & 63, wv = tid >> 6;
    const int ll = lane & 15, lh = lane >> 4;
    const int x0 = blockIdx.x * 16, y0 = blockIdx.y * 4;
    const int t = blockIdx.z;
    const int img = only0 ? t * 4 : t;
    const int row = wv * 16 + ll;

    stage_t(Ysrc + (size_t)img * PPX * 64, x0, y0, lds, tid);
    stage_t(Gpad + (size_t)t * PPX * 64, x0, y0, lds + TSTG, tid);
    bf16x8 Wf[18];
    load_w(Wu, row, 128, 0, lh, Wf);
    __syncthreads();

    f32x4 aU[4], aC[4];
#pragma unroll
    for (int r = 0; r < 4; ++r) {
        aU[r] = (f32x4){0.f, 0.f, 0.f, 0.f};
        aC[r] = (f32x4){0.f, 0.f, 0.f, 0.f};
    }
    conv_pass4(lds, Wf, ll, lh, aU);
    load_w(Wu, row, 128, 64, lh, Wf);
    conv_pass4(lds + TSTG, Wf, ll, lh, aU);
    load_w(Wc, row, 128, 0, lh, Wf);
    conv_pass4(lds, Wf, ll, lh, aC);
    load_w(Wc, row, 128, 64, lh, Wf);
    conv_pass4(lds + TSTG, Wf, ll, lh, aC);

    float ub = bu[row], cb = bc[row];
#pragma unroll
    for (int r = 0; r < 4; ++r)
#pragma unroll
        for (int jj = 0; jj < 4; ++jj) {
            int x = x0 + lh * 4 + jj;
            float u = 1.f / (1.f + __expf(-(aU[r][jj] + ub)));
            float e2 = __expf(2.f * (aC[r][jj] + cb));
            float c = (e2 - 1.f) / (e2 + 1.f);
            Ydst[((size_t)img * PPX + (y0 + r + 1) * PW + (x + 1)) * 64 + row] = f2bf(u * c);
        }
}

// ---------------- final: out[b,h,w,o] = sum_c Ypad[4b][w][79-h][c]*mlp_w[o,c] + mlp_b[o] ----------------
__global__ void final_mlp(const unsigned short* __restrict__ yfin, const float* __restrict__ mw,
                          const float* __restrict__ mb, float* __restrict__ out) {
    int t = blockIdx.x * blockDim.x + threadIdx.x;
    if (t >= 2 * HW * 64) return;
    int o  = t & 63;
    int wv = (t >> 6) % WD;
    int h  = ((t >> 6) / WD) % WD;
    int b  = t / (HW * 64);
    const unsigned short* src = yfin + ((size_t)(b * 4) * PPX + (wv + 1) * PW + (80 - h)) * 64;
    const float* wrow = mw + o * 64;
    float r = mb[o];
#pragma unroll
    for (int c8 = 0; c8 < 8; ++c8) {
        bf16x8 v = *(const bf16x8*)(src + c8 * 8);
#pragma unroll
        for (int k = 0; k < 8; ++k)
            r += bf2f(((const unsigned short*)&v)[k]) * wrow[c8 * 8 + k];
    }
    out[t] = r;
}

extern "C" void kernel_launch(void* const* d_in, const int* in_sizes, int n_in,
                              void* d_out, int out_size, void* d_ws, size_t ws_size,
                              hipStream_t stream) {
    const float* x       = (const float*)d_in[0];
    const float* P       = (const float*)d_in[2];
    const float* msg_w   = (const float*)d_in[4];
    const float* msg_b   = (const float*)d_in[5];
    const float* gates_w = (const float*)d_in[6];
    const float* gates_b = (const float*)d_in[7];
    const float* can_w   = (const float*)d_in[8];
    const float* can_b   = (const float*)d_in[9];
    const float* mlp_w   = (const float*)d_in[10];
    const float* mlp_b   = (const float*)d_in[11];
    float* out = (float*)d_out;

    char* wsb = (char*)d_ws;
    float* mats = (float*)wsb;                              // 1024 B
    float* mask = (float*)(wsb + 1024);                     // 819200
    unsigned short* Wn = (unsigned short*)(wsb + 820224);   // 73728
    unsigned short* We = Wn + 36864;                        // 73728
    unsigned short* Wu = We + 36864;                        // 147456
    unsigned short* Wc = Wu + 73728;                        // 147456
    unsigned short* Y0 = Wc + 73728;                        // 8*PPX*128 = 6952960 ┐
    unsigned short* Y1 = Y0 + (size_t)NIMG * PPX * 64;      // 6952960            ├ 24 contiguous images
    unsigned short* Gpad = Y1 + (size_t)NIMG * PPX * 64;    // 6952960            ┘
    unsigned short* warped = Gpad + (size_t)NIMG * PPX * 64; // 32*PPX*128 = 27811840

    // one mega-prologue: border-zero (243) | mats+mask (32) | repack (864) | rot (640)
    prologue_all<<<243 + 32 + 864 + 640, 256, 0, stream>>>(P, mats, mask,
        msg_w, gates_w, can_w, Wn, We, Wu, Wc, x, Y0);

    // ---- iteration 0 (all 8 targets) ----
    warp_pairs<<<(32 * 6724 * 8 + 255) / 256, 256, 0, stream>>>(Y0, mats, warped, 32 * 6724 * 8, 0);
    msg_agg<<<dim3(5, 20, 8), 256, 0, stream>>>(warped, Y0, mask, Wn, We, msg_b, Gpad, 0);
    gru_conv<<<dim3(5, 20, 8), 256, 0, stream>>>(Y0, Gpad, Wu, Wc, gates_b + 64, can_b, Y1, 0);

    // ---- iteration 1 (only j=0 targets: images 0 and 4) ----
    warp_pairs<<<(8 * 6724 * 8 + 255) / 256, 256, 0, stream>>>(Y1, mats, warped, 8 * 6724 * 8, 1);
    msg_agg<<<dim3(5, 20, 2), 256, 0, stream>>>(warped, Y1, mask, Wn, We, msg_b, Gpad, 1);
    gru_conv<<<dim3(5, 20, 2), 256, 0, stream>>>(Y1, Gpad, Wu, Wc, gates_b + 64, can_b, Y0, 1);

    final_mlp<<<(2 * HW * 64 + 255) / 256, 256, 0, stream>>>(Y0, mlp_w, mlp_b, out);
}